// Round 10
// baseline (533.131 us; speedup 1.0000x reference)
//
#include <hip/hip_runtime.h>
#include <hip/hip_bf16.h>

#define BATCH 16
#define NN 1024
#define MM 1024
#define DD 512

#define LOG2E 1.4426950408889634f
#define LN2f  0.6931471805599453f
#define NEGS  -1.442695e9f   // NEG (-1e9) scaled by log2e; acts as -inf sentinel

// DP geometry (r9, verified 348 us standalone): 4 waves/batch, 4 rows x 1 col
// per lane, DSTAG=96, barrier every 32 (gap 33 => >=1 barrier between ring
// write and read; WAR margin 223), PF=8, chain cuts (single-shuffle, "1+"
// lse3, c1 folding).
#define DSTAG 96
#define PF    8
#define GTOT  1376            // g_last = 1023 + 3*96 + 63 = 1374; mult of 32

#define NPROD 240             // producer blocks; grid = 16 DP + 240 = 256 = #CUs

typedef __bf16 v8bf __attribute__((ext_vector_type(8)));
typedef __bf16 v4bf __attribute__((ext_vector_type(4)));
typedef float  v4f  __attribute__((ext_vector_type(4)));

// ---------------------------------------------------------------- flag zero
// flags layout (ints): conv_cnt[16] | tile_cnt[16*8] | acc[16] (float bits)
__global__ void zero_flags(int* f) {
    if (threadIdx.x < 176) f[threadIdx.x] = 0;
}

// ------------------------------------------------------------- mega kernel
// Grid 256 = #CUs, and the 96 KiB static LDS block FORCES <=1 block/CU
// (LDS pool 160 KiB): placement-proof fix for r8's packing pathology (DP
// blocks sharing CUs with producers stretched the latency-bound DP chain,
// causing the 584us mean / 30ms tail). DP blocks (bid 0..15) thus own their
// CUs; producers (bid 16..255) each run 2-3 conv chunks then 4-5 GEMM tiles
// in col-block-major order (tiles 0..127 = col-block 0 of all batches done
// in producer round 1 -> DP starts ~30us in).
// Cross-block protocol (verified absmax-0 in r7/r8):
//   producer:  __syncthreads (drains stores) -> release fence agent ->
//              atomicAdd(counter)
//   consumer:  relaxed agent atomic-load spin -> acquire fence agent -> read.
// Deadlock-free: 256 blocks <= 256 CUs at 1/CU => all resident; producers
// never wait on DP; GEMM waits only on conv counters completed unconditionally.
__global__ __launch_bounds__(256, 1) void mega(
        const float* __restrict__ zx, const float* __restrict__ zy,
        const float* __restrict__ gw, const float* __restrict__ gap_b,
        __bf16* __restrict__ zxb, __bf16* __restrict__ zyb,
        float* __restrict__ thetaT, int* __restrict__ flags,
        float* __restrict__ out) {
    int* conv_cnt = flags;                  // [16]  (==32 when batch staged)
    int* tile_cnt = flags + 16;             // [16][8] (==8 when col-block done)
    float* acc    = (float*)(flags + 144);  // [16]

    // 96 KiB static LDS: occupancy limiter (only 20 KiB actually used).
    __shared__ __align__(16) char smbuf[98304];
    __bf16* As   = (__bf16*)smbuf;                 // [128*32] producer staging
    __bf16* Bs   = (__bf16*)(smbuf + 8192);        // [128*32]
    float (*ring)[256] = (float(*)[256])smbuf;     // DP ring [3][256]
    float* wsum  = (float*)(smbuf + 16384);        // conv partial sums [4]

    const int bid = blockIdx.x;
    const int tid = threadIdx.x;

    if (bid >= 16) {
        const int p = bid - 16;             // 0..239
        //================= producer: conv chunks ==========================
        for (int cidx = p; cidx < 512; cidx += NPROD) {
            const int chunk = cidx & 15, cb = (cidx >> 4) & 15, which = cidx >> 8;
            const float* src = which ? zy : zx;
            __bf16* dst = which ? zyb : zxb;
            const float* gwp = gw + which * DD;
            const size_t base = ((size_t)cb * NN + (size_t)chunk * 64) * DD;
            const int col = (tid * 4) & (DD - 1);
            const float4 gv = *(const float4*)(gwp + col);
            float sum = 0.0f;
            #pragma unroll 4
            for (int it = 0; it < 32; ++it) {
                size_t off = base + (size_t)it * 1024 + tid * 4;
                float4 x = *(const float4*)(src + off);
                sum += x.x * gv.x + x.y * gv.y + x.z * gv.z + x.w * gv.w;
                v4bf o = { (__bf16)x.x, (__bf16)x.y, (__bf16)x.z, (__bf16)x.w };
                *(v4bf*)(dst + off) = o;
            }
            #pragma unroll
            for (int o = 32; o > 0; o >>= 1) sum += __shfl_down(sum, o);
            if ((tid & 63) == 0) wsum[tid >> 6] = sum;
            __syncthreads();                 // also drains the dst stores
            if (tid == 0) {
                float s = wsum[0] + wsum[1] + wsum[2] + wsum[3];
                atomicAdd(acc + cb, s * (1.0f / 1024.0f));
                __builtin_amdgcn_fence(__ATOMIC_RELEASE, "agent");
                atomicAdd(conv_cnt + cb, 1);
            }
            __syncthreads();                 // wsum reuse guard (loop)
        }
        //================= producer: GEMM tiles (col-block-major) =========
        const int lane = tid & 63, wave = tid >> 6;
        const int wr = wave >> 1, wc = wave & 1;
        const int mrow = lane & 15, quad = lane >> 4;
        const int arow = wave * 32 + (lane >> 2);
        const int acol = (lane & 3) * 8;
        #pragma unroll 1
        for (int T = p; T < 1024; T += NPROD) {
            const int by = T >> 7, rem = T & 127;      // by = DP col-block
            const int bb = rem >> 3, bx = rem & 7;
            while (__hip_atomic_load(conv_cnt + bb, __ATOMIC_RELAXED,
                                     __HIP_MEMORY_SCOPE_AGENT) < 32)
                __builtin_amdgcn_s_sleep(8);
            __builtin_amdgcn_fence(__ATOMIC_ACQUIRE, "agent");

            const int i0 = by * 128, j0 = bx * 128;
            const __bf16* ap = zyb + ((size_t)bb * NN + i0) * DD;
            const __bf16* bp = zxb + ((size_t)bb * MM + j0) * DD;
            v4f gac[4][4] = {};
            for (int kk = 0; kk < DD; kk += 32) {
                __syncthreads();
                #pragma unroll
                for (int i = 0; i < 2; ++i) {
                    const __bf16* ga = ap + (size_t)(arow + 16 * i) * DD + kk + acol;
                    const __bf16* gb = bp + (size_t)(arow + 16 * i) * DD + kk + acol;
                    __builtin_amdgcn_global_load_lds(
                        (const __attribute__((address_space(1))) void*)ga,
                        (__attribute__((address_space(3))) void*)(As + wave * 1024 + i * 512),
                        16, 0, 0);
                    __builtin_amdgcn_global_load_lds(
                        (const __attribute__((address_space(1))) void*)gb,
                        (__attribute__((address_space(3))) void*)(Bs + wave * 1024 + i * 512),
                        16, 0, 0);
                }
                __syncthreads();
                v8bf af[4];
                #pragma unroll
                for (int m = 0; m < 4; ++m)
                    af[m] = *(const v8bf*)&As[(wr * 64 + m * 16 + mrow) * 32 + quad * 8];
                #pragma unroll
                for (int n = 0; n < 4; ++n) {
                    v8bf bf = *(const v8bf*)&Bs[(wc * 64 + n * 16 + mrow) * 32 + quad * 8];
                    #pragma unroll
                    for (int m = 0; m < 4; ++m)
                        gac[m][n] = __builtin_amdgcn_mfma_f32_16x16x32_bf16(af[m], bf, gac[m][n], 0, 0, 0);
                }
            }
            const size_t tbo = (size_t)bb * NN * MM;
            #pragma unroll
            for (int n = 0; n < 4; ++n) {
                int j = j0 + wc * 64 + n * 16 + mrow;
                #pragma unroll
                for (int m = 0; m < 4; ++m) {
                    #pragma unroll
                    for (int r = 0; r < 4; ++r) {
                        int i = i0 + wr * 64 + m * 16 + quad * 4 + r;
                        thetaT[tbo + (size_t)i * MM + j] = gac[m][n][r];
                    }
                }
            }
            __syncthreads();               // drains all waves' theta stores
            if (tid == 0) {
                __builtin_amdgcn_fence(__ATOMIC_RELEASE, "agent");
                atomicAdd(tile_cnt + bb * 8 + by, 1);
            }
        }
        return;
    }

    //================= DP consumer block (batch = bid) ====================
    const int bb = bid;
    const int t = tid & 63, w = tid >> 6;
    // startup: first theta col-block (implies conv + acc final for bb)
    while (__hip_atomic_load(tile_cnt + bb * 8, __ATOMIC_RELAXED,
                             __HIP_MEMORY_SCOPE_AGENT) < 8)
        __builtin_amdgcn_s_sleep(32);
    __builtin_amdgcn_fence(__ATOMIC_ACQUIRE, "agent");

    const float Ac = (acc[bb] + gap_b[0]) * LOG2E;
    const int row0 = w * 256 + t * 4;
    const int off = w * DSTAG + t;
    const float* Tb = thetaT + (size_t)bb * NN * MM + row0;

    float v[4];
    v[0] = v[1] = v[2] = v[3] = NEGS;
    float v3c = NEGS;                       // bottom-row value, prev iter
    float tcp = NEGS;                       // prev iteration's tc (post-fixup)
    float rtc = NEGS;                       // prefetched ring value (lane 0)

    float4 pfr[PF];
    #pragma unroll
    for (int u = 0; u < PF; ++u) {
        int c0 = u - off;
        c0 = c0 < 0 ? 0 : c0;               // cols 0..7: covered by col-block 0
        pfr[u] = *(const float4*)(Tb + (size_t)c0 * NN);
    }

    int last_ready = 1;                     // col-blocks [0,last_ready) ready
    for (int gg = 0; gg < GTOT; gg += PF) {
        // progressive availability: window [gg,gg+8) issues loads of cols <= gg+15
        if (last_ready < 8) {
            int need = (gg + 15) >> 7;
            if (need > 7) need = 7;
            if (need >= last_ready) {
                while (__hip_atomic_load(tile_cnt + bb * 8 + need, __ATOMIC_RELAXED,
                                         __HIP_MEMORY_SCOPE_AGENT) < 8)
                    __builtin_amdgcn_s_sleep(16);
                __builtin_amdgcn_fence(__ATOMIC_ACQUIRE, "agent");
                last_ready = need + 1;
            }
        }
        #pragma unroll
        for (int u = 0; u < PF; ++u) {
            const int g = gg + u;
            const int c = g - off;

            float tc = __shfl_up(v3c, 1);   // up input: neighbor bottom @ c
            if (t == 0) tc = (w == 0) ? NEGS : rtc;
            float tp = tcp;                 // diag input: prev iteration's tc
            if (t == 0 && c == 0) tp = (w == 0) ? 0.0f : NEGS;
            tcp = tc;

            const float4 cur = pfr[u];
            int cn = g + PF - off;          // re-issue this slot: col g+PF
            cn = cn < 0 ? 0 : (cn > MM - 1 ? MM - 1 : cn);
            pfr[u] = *(const float4*)(Tb + (size_t)cn * NN);

            if ((unsigned)c < MM) {
                const float* th = (const float*)&cur;
                float lfA0 = v[0] + Ac, lfA1 = v[1] + Ac;
                float lfA2 = v[2] + Ac, lfA3 = v[3] + Ac;
                float uu = tc + Ac;
                float dg = tp;
                #pragma unroll
                for (int k = 0; k < 4; ++k) {
                    float lf = k == 0 ? lfA0 : (k == 1 ? lfA1 : (k == 2 ? lfA2 : lfA3));
                    float mx = fmaxf(fmaxf(uu, dg), lf);
                    float md = __builtin_amdgcn_fmed3f(uu, dg, lf);
                    float mn = fminf(fminf(uu, dg), lf);
                    float ss = 1.0f + __builtin_amdgcn_exp2f(md - mx)
                                    + __builtin_amdgcn_exp2f(mn - mx);
                    float l  = __builtin_amdgcn_logf(ss);
                    float c1 = fmaf(th[k], LOG2E, mx);
                    float nd = v[k];
                    v[k] = l + c1;
                    uu   = l + (c1 + Ac);
                    dg = nd;
                }
                v3c = v[3];
                if (t == 63 && w < 3) ring[w][c & 255] = v[3];
            }

            if ((g & 31) == 31) __syncthreads();

            // ring prefetch for iteration g+1 (producer wrote the column 33
            // iterations earlier; >=1 barrier strictly between).
            if (t == 0 && w > 0) {
                int cnx = g + 1 - off;
                rtc = ring[w - 1][cnx & 255];
            }
        }
    }
    if (tid == 255) out[bb] = v[3] * LN2f;
}

// ---------------------------------------------------------------- launcher
extern "C" void kernel_launch(void* const* d_in, const int* in_sizes, int n_in,
                              void* d_out, int out_size, void* d_ws, size_t ws_size,
                              hipStream_t stream) {
    const float* zx    = (const float*)d_in[0];
    const float* zy    = (const float*)d_in[1];
    const float* gw    = (const float*)d_in[2];
    const float* gapb  = (const float*)d_in[3];
    float* out = (float*)d_out;

    char* ws = (char*)d_ws;
    float*  thetaT = (float*)ws;                                  // 67,108,864 B
    __bf16* zxb   = (__bf16*)(ws + (size_t)67108864);             // 16,777,216 B
    __bf16* zyb   = (__bf16*)(ws + (size_t)67108864 + 16777216);  // 16,777,216 B
    int*    flags = (int*)(ws + (size_t)67108864 + 2 * 16777216); // 704 B

    zero_flags<<<1, 256, 0, stream>>>(flags);
    mega<<<16 + NPROD, 256, 0, stream>>>(zx, zy, gw, gapb, zxb, zyb, thetaT, flags, out);
}